// Round 8
// baseline (339.441 us; speedup 1.0000x reference)
//
#include <hip/hip_runtime.h>
#include <math.h>

#define N_NODES 50000
#define E_ORIG  500000
#define E_TOT   550000
#define NB      196   // scan blocks: 196*256 = 50176 >= N_NODES

typedef _Float16 half8 __attribute__((ext_vector_type(8)));
typedef _Float16 half4 __attribute__((ext_vector_type(4)));
typedef float    v4f   __attribute__((ext_vector_type(4)));

// ------------------------------------------------------------------
// CSR build (group edges by destination node)
// ------------------------------------------------------------------
__global__ void k_count(const int* __restrict__ ei, int* __restrict__ deg) {
    int e = blockIdx.x * blockDim.x + threadIdx.x;
    if (e >= E_TOT) return;
    int d = (e < E_ORIG) ? ei[E_ORIG + e] : (e - E_ORIG);
    atomicAdd(&deg[d], 1);
}

__global__ __launch_bounds__(256) void k_blocksum(const int* __restrict__ deg,
                                                  int* __restrict__ bsum) {
    int t = threadIdx.x;
    int i = blockIdx.x * 256 + t;
    int v = (i < N_NODES) ? deg[i] : 0;
#pragma unroll
    for (int mk = 1; mk < 64; mk <<= 1) v += __shfl_xor(v, mk, 64);
    __shared__ int ws[4];
    if ((t & 63) == 0) ws[t >> 6] = v;
    __syncthreads();
    if (t == 0) bsum[blockIdx.x] = ws[0] + ws[1] + ws[2] + ws[3];
}

__global__ __launch_bounds__(256) void k_scanbsum(const int* __restrict__ bsum,
                                                  int* __restrict__ boff) {
    __shared__ int s[256];
    int t = threadIdx.x;
    int v = (t < NB) ? bsum[t] : 0;
    s[t] = v;
    __syncthreads();
    for (int o = 1; o < 256; o <<= 1) {
        int x = (t >= o) ? s[t - o] : 0;
        __syncthreads();
        s[t] += x;
        __syncthreads();
    }
    if (t <= NB) boff[t] = (t == 0) ? 0 : s[t - 1];
}

__global__ __launch_bounds__(256) void k_offsets(const int* __restrict__ deg,
                                                 const int* __restrict__ boff,
                                                 int* __restrict__ offsets,
                                                 int* __restrict__ cur) {
    __shared__ int s[256];
    int t = threadIdx.x;
    int i = blockIdx.x * 256 + t;
    int v = (i < N_NODES) ? deg[i] : 0;
    s[t] = v;
    __syncthreads();
    for (int o = 1; o < 256; o <<= 1) {
        int x = (t >= o) ? s[t - o] : 0;
        __syncthreads();
        s[t] += x;
        __syncthreads();
    }
    int off = boff[blockIdx.x] + s[t] - v;  // exclusive
    if (i <= N_NODES) {
        offsets[i] = off;
        if (i < N_NODES) cur[i] = off;
    }
}

__global__ void k_scatter(const int* __restrict__ ei, int* __restrict__ cur,
                          int* __restrict__ csr_src, int* __restrict__ csr_dst) {
    int e = blockIdx.x * blockDim.x + threadIdx.x;
    if (e >= E_TOT) return;
    int s, d;
    if (e < E_ORIG) { s = ei[e]; d = ei[E_ORIG + e]; }
    else            { s = e - E_ORIG; d = s; }
    int slot = atomicAdd(&cur[d], 1);
    csr_src[slot] = s;
    csr_dst[slot] = d;
}

// ------------------------------------------------------------------
// Fused prep: zero deg, W1/W2 transpose+cast, vs2/vd2 = W2 @ a2
// ------------------------------------------------------------------
__global__ void k_prepw(const float* __restrict__ W1, const float* __restrict__ W2,
                        const float* __restrict__ as2, const float* __restrict__ ad2,
                        _Float16* __restrict__ w1t, _Float16* __restrict__ w2t,
                        float* __restrict__ vs2, float* __restrict__ vd2,
                        int* __restrict__ deg) {
    int i = blockIdx.x * blockDim.x + threadIdx.x;
    if (i < 128 * 256) {
        int k = i >> 8, c = i & 255;
        w1t[(size_t)c * 128 + k] = (_Float16)W1[i];
        return;
    }
    int j = i - 128 * 256;
    if (j < 256 * 256) {
        int k = j >> 8, c = j & 255;
        w2t[(size_t)c * 256 + k] = (_Float16)W2[j];
        return;
    }
    j -= 256 * 256;
    if (j < 256) {
        float s = 0.f, d = 0.f;
        for (int c = 0; c < 256; c++) {
            float w = W2[(size_t)j * 256 + c];
            s += w * as2[c];
            d += w * ad2[c];
        }
        vs2[j] = s;
        vd2[j] = d;
        return;
    }
    j -= 256;
    if (j < N_NODES) deg[j] = 0;
}

// ------------------------------------------------------------------
// Edge-weight precompute, layer 1: w1w[e][h] = exp(leaky(es+ed)), f32.
// Edge-parallel, 8 threads per edge (one per head), coalesced.
// ------------------------------------------------------------------
__global__ __launch_bounds__(256) void k_wts1(
    const int* __restrict__ csr_src, const int* __restrict__ csr_dst,
    const float* __restrict__ es, const float* __restrict__ ed,
    float* __restrict__ w1w) {
    int i = blockIdx.x * blockDim.x + threadIdx.x;
    if (i >= E_TOT * 8) return;
    int e = i >> 3, h = i & 7;
    int s = csr_src[e], d = csr_dst[e];
    float l = es[(size_t)s * 8 + h] + ed[(size_t)d * 8 + h];
    l = l > 0.f ? l : 0.2f * l;
    w1w[i] = __expf(l);
}

// Edge-weight precompute, layer 2 (single head)
__global__ __launch_bounds__(256) void k_wts2(
    const int* __restrict__ csr_src, const int* __restrict__ csr_dst,
    const float* __restrict__ es2, const float* __restrict__ ed2,
    float* __restrict__ w2w) {
    int e = blockIdx.x * blockDim.x + threadIdx.x;
    if (e >= E_TOT) return;
    float l = es2[csr_src[e]] + ed2[csr_dst[e]];
    l = l > 0.f ? l : 0.2f * l;
    w2w[e] = __expf(l);
}

// ------------------------------------------------------------------
// GEMM1: H[N,256] = cvt16(X[N,128]) @ w1t^T, f16 out via LDS-staged
// streaming stores + fused 8-head es/ed. (validated R7)
// ------------------------------------------------------------------
__global__ __launch_bounds__(256) void k_gemm1(
    const float* __restrict__ X, const _Float16* __restrict__ Bt,
    const float* __restrict__ a_s, const float* __restrict__ a_d,
    _Float16* __restrict__ H, float* __restrict__ es, float* __restrict__ ed) {
    int t = threadIdx.x, w = t >> 6, lane = t & 63;
    int quad = lane >> 4, l16 = lane & 15;
    int row0 = blockIdx.x * 32;
    int colbase = w * 64;

    v4f acc[2][4];
#pragma unroll
    for (int i = 0; i < 2; i++)
#pragma unroll
        for (int j = 0; j < 4; j++) acc[i][j] = (v4f){0.f, 0.f, 0.f, 0.f};

    int r0 = row0 + l16;      if (r0 >= N_NODES) r0 = N_NODES - 1;
    int r1 = row0 + 16 + l16; if (r1 >= N_NODES) r1 = N_NODES - 1;
    const float4* a0p = (const float4*)(X + (size_t)r0 * 128) + quad * 2;
    const float4* a1p = (const float4*)(X + (size_t)r1 * 128) + quad * 2;
    const half8* bp[4];
#pragma unroll
    for (int ct = 0; ct < 4; ct++)
        bp[ct] = (const half8*)(Bt + (size_t)(colbase + ct * 16 + l16) * 128 + quad * 8);

#pragma unroll
    for (int kc = 0; kc < 4; kc++) {
        float4 f0 = a0p[kc * 8], f1 = a0p[kc * 8 + 1];
        float4 f2 = a1p[kc * 8], f3 = a1p[kc * 8 + 1];
        half8 av0 = (half8){(_Float16)f0.x, (_Float16)f0.y, (_Float16)f0.z, (_Float16)f0.w,
                            (_Float16)f1.x, (_Float16)f1.y, (_Float16)f1.z, (_Float16)f1.w};
        half8 av1 = (half8){(_Float16)f2.x, (_Float16)f2.y, (_Float16)f2.z, (_Float16)f2.w,
                            (_Float16)f3.x, (_Float16)f3.y, (_Float16)f3.z, (_Float16)f3.w};
#pragma unroll
        for (int ct = 0; ct < 4; ct++) {
            half8 bv = bp[ct][kc * 4];
            acc[0][ct] = __builtin_amdgcn_mfma_f32_16x16x32_f16(av0, bv, acc[0][ct], 0, 0, 0);
            acc[1][ct] = __builtin_amdgcn_mfma_f32_16x16x32_f16(av1, bv, acc[1][ct], 0, 0, 0);
        }
    }

    float asv[4], adv[4];
#pragma unroll
    for (int ct = 0; ct < 4; ct++) {
        asv[ct] = a_s[colbase + ct * 16 + l16];
        adv[ct] = a_d[colbase + ct * 16 + l16];
    }
#pragma unroll
    for (int rt = 0; rt < 2; rt++) {
#pragma unroll
        for (int hp = 0; hp < 2; hp++) {
#pragma unroll
            for (int reg = 0; reg < 4; reg++) {
                float ps = acc[rt][2 * hp][reg] * asv[2 * hp] +
                           acc[rt][2 * hp + 1][reg] * asv[2 * hp + 1];
                float pd = acc[rt][2 * hp][reg] * adv[2 * hp] +
                           acc[rt][2 * hp + 1][reg] * adv[2 * hp + 1];
#pragma unroll
                for (int mk = 1; mk < 16; mk <<= 1) {
                    ps += __shfl_xor(ps, mk, 64);
                    pd += __shfl_xor(pd, mk, 64);
                }
                if (l16 == 0) {
                    int row = row0 + rt * 16 + quad * 4 + reg;
                    if (row < N_NODES) {
                        int head = w * 2 + hp;
                        es[(size_t)row * 8 + head] = ps;
                        ed[(size_t)row * 8 + head] = pd;
                    }
                }
            }
        }
    }

    __shared__ _Float16 SH[32][264];
#pragma unroll
    for (int rt = 0; rt < 2; rt++)
#pragma unroll
        for (int ct = 0; ct < 4; ct++)
#pragma unroll
            for (int reg = 0; reg < 4; reg++)
                SH[rt * 16 + quad * 4 + reg][colbase + ct * 16 + l16] =
                    (_Float16)acc[rt][ct][reg];
    __syncthreads();
#pragma unroll
    for (int j = 0; j < 4; j++) {
        int c = j * 256 + t;
        int row = c >> 5, col8 = c & 31;
        int gr = row0 + row;
        if (gr < N_NODES)
            *(half8*)(H + (size_t)gr * 256 + col8 * 8) = *(const half8*)&SH[row][col8 * 8];
    }
}

// ------------------------------------------------------------------
// GEMM2: OUT[N,256] = A[N,256] @ w2t^T + bias, f32 out (validated R7)
// ------------------------------------------------------------------
__global__ __launch_bounds__(256) void k_gemm2(
    const _Float16* __restrict__ A, const _Float16* __restrict__ Bt,
    const float* __restrict__ bias, float* __restrict__ OUT) {
    int t = threadIdx.x, w = t >> 6, lane = t & 63;
    int quad = lane >> 4, l16 = lane & 15;
    int row0 = blockIdx.x * 32;
    int colbase = w * 64;

    v4f acc[2][4];
#pragma unroll
    for (int i = 0; i < 2; i++)
#pragma unroll
        for (int j = 0; j < 4; j++) acc[i][j] = (v4f){0.f, 0.f, 0.f, 0.f};

    int r0 = row0 + l16;      if (r0 >= N_NODES) r0 = N_NODES - 1;
    int r1 = row0 + 16 + l16; if (r1 >= N_NODES) r1 = N_NODES - 1;
    const half8* a0 = (const half8*)(A + (size_t)r0 * 256 + quad * 8);
    const half8* a1 = (const half8*)(A + (size_t)r1 * 256 + quad * 8);
    const half8* bp[4];
#pragma unroll
    for (int ct = 0; ct < 4; ct++)
        bp[ct] = (const half8*)(Bt + (size_t)(colbase + ct * 16 + l16) * 256 + quad * 8);

#pragma unroll
    for (int kc = 0; kc < 8; kc++) {
        half8 av0 = a0[kc * 4];
        half8 av1 = a1[kc * 4];
#pragma unroll
        for (int ct = 0; ct < 4; ct++) {
            half8 bv = bp[ct][kc * 4];
            acc[0][ct] = __builtin_amdgcn_mfma_f32_16x16x32_f16(av0, bv, acc[0][ct], 0, 0, 0);
            acc[1][ct] = __builtin_amdgcn_mfma_f32_16x16x32_f16(av1, bv, acc[1][ct], 0, 0, 0);
        }
    }

    __shared__ float SF[32][260];
#pragma unroll
    for (int rt = 0; rt < 2; rt++)
#pragma unroll
        for (int ct = 0; ct < 4; ct++)
#pragma unroll
            for (int reg = 0; reg < 4; reg++)
                SF[rt * 16 + quad * 4 + reg][colbase + ct * 16 + l16] = acc[rt][ct][reg];
    __syncthreads();
#pragma unroll
    for (int j = 0; j < 8; j++) {
        int c = j * 256 + t;
        int row = c >> 6, c4 = c & 63;
        int gr = row0 + row;
        if (gr < N_NODES) {
            float4 v = *(const float4*)&SF[row][c4 * 4];
            float4 bb = ((const float4*)bias)[c4];
            float4 o = make_float4(v.x + bb.x, v.y + bb.y, v.z + bb.z, v.w + bb.w);
            *(float4*)(OUT + (size_t)gr * 256 + c4 * 4) = o;
        }
    }
}

// ------------------------------------------------------------------
// Layer-1 aggregation: wave-per-node, precomputed weights (linear
// reads), 32-bit byte-offset gather addressing. Fused es2/ed2.
// ------------------------------------------------------------------
__global__ __launch_bounds__(256) void k_agg1(
    const _Float16* __restrict__ H1, const float* __restrict__ w1w,
    const int* __restrict__ offsets, const int* __restrict__ csr_src,
    const float* __restrict__ b1, const float* __restrict__ vs2,
    const float* __restrict__ vd2, _Float16* __restrict__ out1,
    float* __restrict__ es2, float* __restrict__ ed2) {
    int t = threadIdx.x, w = t >> 6, lane = t & 63;
    int n = blockIdx.x * 4 + w;  // grid 12500 x 4 waves = 50000 exactly
    int hB = lane >> 3;          // head of this lane's 4 channels
    int beg = offsets[n];
    int deg = offsets[n + 1] - beg;

    const char* __restrict__ Hb = (const char*)H1 + lane * 8;
    const float* __restrict__ pw = w1w + (size_t)beg * 8 + hB;
    float a0 = 0.f, a1 = 0.f, a2 = 0.f, a3 = 0.f, den = 0.f;

    for (int base = 0; base < deg; base += 64) {
        int rem = deg - base; if (rem > 64) rem = 64;
        int idx = beg + base + lane;
        if (idx >= E_TOT) idx = E_TOT - 1;
        int sreg = csr_src[idx];
        int i = 0;
        for (; i + 1 < rem; i += 2) {
            int s0 = __shfl(sreg, i);
            int s1 = __shfl(sreg, i + 1);
            float w0 = pw[(base + i) * 8];
            float w1 = pw[(base + i + 1) * 8];
            half4 h0 = *(const half4*)(Hb + ((unsigned)s0 << 9));
            half4 h1 = *(const half4*)(Hb + ((unsigned)s1 << 9));
            a0 += w0 * (float)h0[0]; a1 += w0 * (float)h0[1];
            a2 += w0 * (float)h0[2]; a3 += w0 * (float)h0[3];
            a0 += w1 * (float)h1[0]; a1 += w1 * (float)h1[1];
            a2 += w1 * (float)h1[2]; a3 += w1 * (float)h1[3];
            den += w0 + w1;
        }
        if (i < rem) {
            int s0 = __shfl(sreg, i);
            float w0 = pw[(base + i) * 8];
            half4 h0 = *(const half4*)(Hb + ((unsigned)s0 << 9));
            a0 += w0 * (float)h0[0]; a1 += w0 * (float)h0[1];
            a2 += w0 * (float)h0[2]; a3 += w0 * (float)h0[3];
            den += w0;
        }
    }

    float r = 1.f / (den + 1e-16f);
    float4 bb = ((const float4*)b1)[lane];
    float o0 = a0 * r + bb.x, o1 = a1 * r + bb.y;
    float o2 = a2 * r + bb.z, o3 = a3 * r + bb.w;
    o0 = o0 > 0.f ? o0 : __expf(o0) - 1.f;
    o1 = o1 > 0.f ? o1 : __expf(o1) - 1.f;
    o2 = o2 > 0.f ? o2 : __expf(o2) - 1.f;
    o3 = o3 > 0.f ? o3 : __expf(o3) - 1.f;
    ((half4*)(out1 + (size_t)n * 256))[lane] =
        (half4){(_Float16)o0, (_Float16)o1, (_Float16)o2, (_Float16)o3};

    // fused layer-2 attention coefficients
    float4 vs = ((const float4*)vs2)[lane];
    float4 vd = ((const float4*)vd2)[lane];
    float ps = o0 * vs.x + o1 * vs.y + o2 * vs.z + o3 * vs.w;
    float pd = o0 * vd.x + o1 * vd.y + o2 * vd.z + o3 * vd.w;
#pragma unroll
    for (int mk = 1; mk < 64; mk <<= 1) {
        ps += __shfl_xor(ps, mk, 64);
        pd += __shfl_xor(pd, mk, 64);
    }
    if (lane == 0) { es2[n] = ps; ed2[n] = pd; }
}

// ------------------------------------------------------------------
// Layer-2 aggregation: wave-per-node, weights ride in the coalesced
// 64-wide window (shfl broadcast, zero per-edge loads).
// ------------------------------------------------------------------
__global__ __launch_bounds__(256) void k_agg2(
    const _Float16* __restrict__ O1, const float* __restrict__ w2w,
    const int* __restrict__ offsets, const int* __restrict__ csr_src,
    _Float16* __restrict__ xagg) {
    int t = threadIdx.x, w = t >> 6, lane = t & 63;
    int n = blockIdx.x * 4 + w;
    int beg = offsets[n];
    int deg = offsets[n + 1] - beg;

    const char* __restrict__ Ob = (const char*)O1 + lane * 8;
    float a0 = 0.f, a1 = 0.f, a2 = 0.f, a3 = 0.f, den = 0.f;

    for (int base = 0; base < deg; base += 64) {
        int rem = deg - base; if (rem > 64) rem = 64;
        int idx = beg + base + lane;
        if (idx >= E_TOT) idx = E_TOT - 1;
        int sreg = csr_src[idx];
        float wreg = w2w[idx];
        int i = 0;
        for (; i + 1 < rem; i += 2) {
            int s0 = __shfl(sreg, i);
            int s1 = __shfl(sreg, i + 1);
            float w0 = __shfl(wreg, i);
            float w1 = __shfl(wreg, i + 1);
            half4 h0 = *(const half4*)(Ob + ((unsigned)s0 << 9));
            half4 h1 = *(const half4*)(Ob + ((unsigned)s1 << 9));
            a0 += w0 * (float)h0[0]; a1 += w0 * (float)h0[1];
            a2 += w0 * (float)h0[2]; a3 += w0 * (float)h0[3];
            a0 += w1 * (float)h1[0]; a1 += w1 * (float)h1[1];
            a2 += w1 * (float)h1[2]; a3 += w1 * (float)h1[3];
            den += w0 + w1;
        }
        if (i < rem) {
            int s0 = __shfl(sreg, i);
            float w0 = __shfl(wreg, i);
            half4 h0 = *(const half4*)(Ob + ((unsigned)s0 << 9));
            a0 += w0 * (float)h0[0]; a1 += w0 * (float)h0[1];
            a2 += w0 * (float)h0[2]; a3 += w0 * (float)h0[3];
            den += w0;
        }
    }

    float r = 1.f / (den + 1e-16f);
    ((half4*)(xagg + (size_t)n * 256))[lane] =
        (half4){(_Float16)(a0 * r), (_Float16)(a1 * r),
                (_Float16)(a2 * r), (_Float16)(a3 * r)};
}

// ------------------------------------------------------------------
extern "C" void kernel_launch(void* const* d_in, const int* in_sizes, int n_in,
                              void* d_out, int out_size, void* d_ws, size_t ws_size,
                              hipStream_t stream) {
    const float* x   = (const float*)d_in[0];
    const int*   ei  = (const int*)d_in[1];
    const float* W1  = (const float*)d_in[2];
    const float* as1 = (const float*)d_in[3];
    const float* ad1 = (const float*)d_in[4];
    const float* b1  = (const float*)d_in[5];
    const float* W2  = (const float*)d_in[6];
    const float* as2 = (const float*)d_in[7];
    const float* ad2 = (const float*)d_in[8];
    const float* b2  = (const float*)d_in[9];
    float* out = (float*)d_out;

    char* ws = (char*)d_ws;
    size_t off = 0;
    auto alloc = [&](size_t bytes) {
        void* p = ws + off;
        off = (off + bytes + 255) & ~(size_t)255;
        return p;
    };
    _Float16* h1h     = (_Float16*)alloc((size_t)N_NODES * 256 * 2);
    _Float16* out1h   = (_Float16*)alloc((size_t)N_NODES * 256 * 2);
    _Float16* xagg    = (_Float16*)alloc((size_t)N_NODES * 256 * 2);
    _Float16* w1t     = (_Float16*)alloc((size_t)128 * 256 * 2);
    _Float16* w2t     = (_Float16*)alloc((size_t)256 * 256 * 2);
    float*    es1     = (float*)alloc((size_t)N_NODES * 8 * 4);
    float*    ed1     = (float*)alloc((size_t)N_NODES * 8 * 4);
    float*    es2     = (float*)alloc((size_t)N_NODES * 4);
    float*    ed2     = (float*)alloc((size_t)N_NODES * 4);
    float*    vs2     = (float*)alloc(256 * 4);
    float*    vd2     = (float*)alloc(256 * 4);
    float*    w1w     = (float*)alloc((size_t)E_TOT * 8 * 4);
    float*    w2w     = (float*)alloc((size_t)E_TOT * 4);
    int*      deg     = (int*)alloc((size_t)N_NODES * 4);
    int*      offsets = (int*)alloc((size_t)(N_NODES + 1) * 4);
    int*      cur     = (int*)alloc((size_t)N_NODES * 4);
    int*      csr_src = (int*)alloc((size_t)E_TOT * 4);
    int*      csr_dst = (int*)alloc((size_t)E_TOT * 4);
    int*      bsum    = (int*)alloc((size_t)NB * 4);
    int*      boff    = (int*)alloc((size_t)(NB + 1) * 4);

    const int TB = 256;
    int gridE = (E_TOT + TB - 1) / TB;
    int gridG = (N_NODES + 31) / 32;   // 32-row GEMM tiles
    int gridA = N_NODES / 4;           // wave-per-node

    // prep (includes deg zeroing) then CSR build
    int prepN = 128 * 256 + 256 * 256 + 256 + N_NODES;
    k_prepw<<<(prepN + TB - 1) / TB, TB, 0, stream>>>(W1, W2, as2, ad2,
                                                      w1t, w2t, vs2, vd2, deg);
    k_count<<<gridE, TB, 0, stream>>>(ei, deg);
    k_blocksum<<<NB, TB, 0, stream>>>(deg, bsum);
    k_scanbsum<<<1, TB, 0, stream>>>(bsum, boff);
    k_offsets<<<NB, TB, 0, stream>>>(deg, boff, offsets, cur);
    k_scatter<<<gridE, TB, 0, stream>>>(ei, cur, csr_src, csr_dst);

    // layer 1
    k_gemm1<<<gridG, TB, 0, stream>>>(x, w1t, as1, ad1, h1h, es1, ed1);
    k_wts1<<<(E_TOT * 8 + TB - 1) / TB, TB, 0, stream>>>(csr_src, csr_dst,
                                                         es1, ed1, w1w);
    k_agg1<<<gridA, TB, 0, stream>>>(h1h, w1w, offsets, csr_src, b1,
                                     vs2, vd2, out1h, es2, ed2);

    // layer 2: weights, aggregate (linearity), GEMM straight to d_out
    k_wts2<<<gridE, TB, 0, stream>>>(csr_src, csr_dst, es2, ed2, w2w);
    k_agg2<<<gridA, TB, 0, stream>>>(out1h, w2w, offsets, csr_src, xagg);
    k_gemm2<<<gridG, TB, 0, stream>>>(xagg, w2t, b2, out);
}